// Round 9
// baseline (466.796 us; speedup 1.0000x reference)
//
#include <hip/hip_runtime.h>
#include <hip/hip_bf16.h>
#include <math.h>

// Problem constants
#define N_E      16384
#define E_DIM    64
#define GROUPS   4
#define N_E_G    4096
#define NQ       16384     // B*H*W query vectors

// Output layout (element offsets into d_out, float32)
#define OFF_QUANT   0L
#define OFF_VQLOSS  4194304L
#define OFF_PERP    4194316L
#define OFF_MINENC  4194317L
#define OFF_IDX     71303181L
// zero region [OFF_VQLOSS, OFF_IDX): 67,108,877 floats, 16B-aligned start.
// 512 slices x 32768 float4 cover 67,108,864; 13-float tail by slice 0.

// Workspace layout (element offsets into d_ws as float*/int*)
#define WS_EN     0L          // normalized emb fp32 [4][4096][64]
#define WS_EN2    1048576L    // |e|^2 per code [16384]
#define WS_ENHI   1064960L    // bf16(en) ushort [4][4096][64] -> 524288 floats
#define WS_HIST   1589248L    // int[4096]
#define WS_IDX3   1593344L    // int[16384]

typedef float  float4v  __attribute__((ext_vector_type(4)));
typedef short  short8   __attribute__((ext_vector_type(8)));

static __device__ __forceinline__ ushort f2bf(float x) {
    union { __hip_bfloat16 h; ushort u; } cv; cv.h = __float2bfloat16(x);
    return cv.u;
}

// ---------------------------------------------------------------------------
// K0: blocks [0,4096) normalize embedding (one wave per code);
// block 4096 zeroes hist.
__global__ void norm_emb_kernel(const float* __restrict__ emb,
                                float* __restrict__ en, float* __restrict__ en2,
                                ushort* __restrict__ ehi, int* __restrict__ hist) {
    const int t = threadIdx.x;
    if (blockIdx.x == 4096) {
        for (int i = t; i < N_E_G; i += 256) hist[i] = 0;
        return;
    }
    int gid  = blockIdx.x * 256 + t;
    int code = gid >> 6;
    int k    = t & 63;
    float x = emb[code * 64 + k];
    float ss = x * x;
    #pragma unroll
    for (int off = 32; off; off >>= 1) ss += __shfl_xor(ss, off, 64);
    float v = x / fmaxf(sqrtf(ss), 1e-12f);
    en[code * 64 + k]  = v;
    ehi[code * 64 + k] = f2bf(v);
    float s2 = v * v;
    #pragma unroll
    for (int off = 32; off; off >>= 1) s2 += __shfl_xor(s2, off, 64);
    if (k == 0) en2[code] = s2;
}

// ---------------------------------------------------------------------------
// K1: fused z-norm + bf16-hi MFMA candidate generation + exact fp32 rescore.
// 512 blocks (128 queries x group), 512 threads = 8 waves (4 q-quarters x
// 2 code-halves), 2 blocks/CU => 16 waves/CU.
// KEY CHANGE vs round 8: the 512 KB zero-fill slice moved OUT of the K-loop
// to the kernel tail (after all loads), because loads and stores share the
// vmcnt FIFO on CDNA — in-loop fill stores forced every tile's MFMA waitcnt
// to drain the previous tile's HBM write-acks (~14k cyc/tile observed).
// Tail stores are fire-and-forget until s_endpgm; 2 blocks/CU stagger the
// write tail against the other block's compute.
// TAU >= 2*E, E = worst-case |dot - bf16hi-dot| <= 2*2^-8*(1+eps) = 7.83e-3.
#define CAP  64
#define TAU  0.017f
__global__ __launch_bounds__(512, 4)
void vq_cand_kernel(const float* __restrict__ z, const ushort* __restrict__ ehi,
                    const float* __restrict__ en, const float* __restrict__ en2,
                    float* __restrict__ out,
                    int* __restrict__ hist, int* __restrict__ idx3) {
    __shared__ float  ztile[64][129];    // raw z, [d][q]
    __shared__ float  rden[128];
    __shared__ int    cnt[128];
    __shared__ ushort cand[128 * CAP];   // 16 KB
    __shared__ int    bks[128];

    const int g  = blockIdx.y;
    const int q0 = blockIdx.x * 128;
    const int t  = threadIdx.x;
    const int lane = t & 63;
    const int wave = t >> 6;
    const int l15 = lane & 15, quad = lane >> 4;
    const int qh = wave & 3;       // query quarter (32 queries)
    const int cq = wave >> 2;      // code half of each 128-tile (64 codes)

    const int sliceId = g * 128 + blockIdx.x;    // 0..511
    float4v* fill4 = (float4v*)(out + OFF_VQLOSS) + (size_t)sliceId * 32768;
    const float4v z4 = {0.f, 0.f, 0.f, 0.f};

    // stage raw z tile: [d][q], coalesced along hw
    {
        int b = q0 >> 10, hw0 = q0 & 1023;
        const float* zsrc = z + (size_t)b * 262144 + (size_t)g * 65536 + hw0;
        for (int i = t; i < 64 * 128; i += 512) {
            int d = i >> 7, q = i & 127;
            ztile[d][q] = zsrc[(size_t)d * 1024 + q];
        }
    }
    if (t < 128) cnt[t] = 0;
    __syncthreads();

    // per-query norms (sequential over d — bit-identical to rounds 1-8)
    if (t < 128) {
        float ss = 0.f;
        for (int d = 0; d < 64; ++d) {
            float x = ztile[d][t];
            ss = fmaf(x, x, ss);
        }
        rden[t] = fmaxf(sqrtf(ss), 1e-12f);
    }
    __syncthreads();

    // B-frags: this wave's 32 queries (2 x 16), built from LDS
    short8 bfrag[2][2];
    #pragma unroll
    for (int u = 0; u < 2; ++u) {
        int q = qh * 32 + u * 16 + l15;
        float den = rden[q];
        #pragma unroll
        for (int ks = 0; ks < 2; ++ks) {
            short8 f;
            #pragma unroll
            for (int j = 0; j < 8; ++j) {
                int k = ks * 32 + quad * 8 + j;
                f[j] = (short)f2bf(ztile[k][q] / den);
            }
            bfrag[u][ks] = f;
        }
    }

    // A-operand base: code row cq*64 + l15, k-chunk quad*8
    const ushort* abase = ehi + (size_t)g * N_E_G * 64
                        + (size_t)(cq * 64 + l15) * 64 + quad * 8;

    float Mrun[2];
    Mrun[0] = -3.4e38f; Mrun[1] = -3.4e38f;

    for (int tile = 0; tile < 32; ++tile) {
        // A-frags for this tile (per-lane dense loads from L2)
        short8 af[4][2];
        {
            const ushort* p = abase + (size_t)(tile * 128) * 64;
            #pragma unroll
            for (int cs = 0; cs < 4; ++cs)
                #pragma unroll
                for (int ks = 0; ks < 2; ++ks)
                    af[cs][ks] = *(const short8*)(p + (size_t)(cs * 16) * 64 + ks * 32);
        }

        float4v acc[4][2];
        #pragma unroll
        for (int cs = 0; cs < 4; ++cs)
            #pragma unroll
            for (int u = 0; u < 2; ++u) {
                float4v zz = {0.f, 0.f, 0.f, 0.f};
                float4v tmp = __builtin_amdgcn_mfma_f32_16x16x32_bf16(
                                  af[cs][0], bfrag[u][0], zz, 0, 0, 0);
                acc[cs][u] = __builtin_amdgcn_mfma_f32_16x16x32_bf16(
                                  af[cs][1], bfrag[u][1], tmp, 0, 0, 0);
            }

        // epilogue: running per-query max over the 64-code column + capture
        const int j0 = tile * 128;
        #pragma unroll
        for (int u = 0; u < 2; ++u) {
            float m = acc[0][u][0];
            #pragma unroll
            for (int cs = 0; cs < 4; ++cs)
                #pragma unroll
                for (int r = 0; r < 4; ++r) m = fmaxf(m, acc[cs][u][r]);
            float m2 = fmaxf(m, __shfl_xor(m, 16, 64));
            float m4 = fmaxf(m2, __shfl_xor(m2, 32, 64));
            Mrun[u] = fmaxf(Mrun[u], m4);
            float thr = Mrun[u] - TAU;
            if (m >= thr) {                    // rare
                int ql = qh * 32 + u * 16 + l15;
                #pragma unroll
                for (int cs = 0; cs < 4; ++cs)
                    #pragma unroll
                    for (int r = 0; r < 4; ++r)
                        if (acc[cs][u][r] >= thr) {
                            int cidx = j0 + cq * 64 + cs * 16 + quad * 4 + r;
                            int slot = atomicAdd(&cnt[ql], 1);
                            if (slot < CAP) cand[ql * CAP + slot] = (ushort)cidx;
                        }
            }
        }
    }
    __syncthreads();

    // exact fp32 rescore (verified ordering/tie-break: first-wins == min idx)
    if (t < 128) {
        int q = q0 + t;
        float den = rden[t];
        float za[64];
        #pragma unroll
        for (int k = 0; k < 64; ++k) za[k] = ztile[k][t] / den;
        int nc = cnt[t]; if (nc > CAP) nc = CAP;
        float best = -3.4e38f; int bk = 0x7fffffff;
        for (int s = 0; s < nc; ++s) {
            int c = cand[t * CAP + s];
            const float* ev = en + ((size_t)g * N_E_G + c) * 64;
            float a = 0.f;
            #pragma unroll
            for (int k = 0; k < 64; ++k) a = fmaf(za[k], ev[k], a);
            float d = 2.f * a - en2[g * N_E_G + c];
            if (d > best || (d == best && c < bk)) { best = d; bk = c; }
        }
        if (bk == 0x7fffffff) bk = 0;
        bks[t] = bk;
        out[OFF_IDX + (size_t)q * 4 + g] = (float)bk;
        if (g == 3) {
            idx3[q] = bk;
            atomicAdd(&hist[bk], 1);
        }
    }
    __syncthreads();

    // quant write, coalesced along hw
    for (int i = t; i < 128 * 64; i += 512) {
        int d = i >> 7, m = i & 127;
        int n = q0 + m, b = n >> 10, hw = n & 1023;
        out[OFF_QUANT + (size_t)b * 262144 + (size_t)(g * 64 + d) * 1024 + hw] =
            en[((size_t)g * N_E_G + bks[m]) * 64 + d];
    }

    // ---- TAIL: zero-fill this block's 512 KB slice of the zero region.
    // Fire-and-forget: no loads follow, so no waitcnt drains these until
    // s_endpgm. 64 float4 stores per thread, fully coalesced.
    #pragma unroll 8
    for (int i = 0; i < 64; ++i)
        fill4[(size_t)i * 512 + t] = z4;

    // 13-float tail of the zero region
    if (sliceId == 0 && t < 13) out[OFF_VQLOSS + 67108864L + t] = 0.f;
}

// ---------------------------------------------------------------------------
// K2: scatter ones (64 blocks) + perplexity (block 64). Stream-ordered after
// vq_cand, so the zero-fill is complete and hist is final.
__global__ void finalize_kernel(const int* __restrict__ idx3,
                                const int* __restrict__ hist,
                                float* __restrict__ out) {
    if (blockIdx.x < 64) {
        int r = blockIdx.x * 256 + threadIdx.x;
        out[OFF_MINENC + (size_t)r * N_E_G + idx3[r]] = 1.0f;
        return;
    }
    __shared__ float s[256];
    int t = threadIdx.x;
    float acc = 0.f;
    for (int k = t; k < N_E_G; k += 256) {
        float p = (float)hist[k] * (1.0f / 16384.0f);
        acc += p * logf(p + 1e-10f);
    }
    s[t] = acc;
    __syncthreads();
    for (int o = 128; o; o >>= 1) {
        if (t < o) s[t] += s[t + o];
        __syncthreads();
    }
    if (t == 0) out[OFF_PERP] = expf(-s[0]);
}

// ---------------------------------------------------------------------------
extern "C" void kernel_launch(void* const* d_in, const int* in_sizes, int n_in,
                              void* d_out, int out_size, void* d_ws, size_t ws_size,
                              hipStream_t stream) {
    const float* z_groups = (const float*)d_in[0];
    const float* emb      = (const float*)d_in[1];
    float* out = (float*)d_out;
    float* ws  = (float*)d_ws;

    float*  en   = ws + WS_EN;
    float*  en2  = ws + WS_EN2;
    ushort* ehi  = (ushort*)(ws + WS_ENHI);
    int*    hist = (int*)(ws + WS_HIST);
    int*    idx3 = (int*)(ws + WS_IDX3);

    norm_emb_kernel<<<4097, 256, 0, stream>>>(emb, en, en2, ehi, hist);

    vq_cand_kernel<<<dim3(NQ / 128, GROUPS), 512, 0, stream>>>(
        z_groups, ehi, en, en2, out, hist, idx3);

    finalize_kernel<<<65, 256, 0, stream>>>(idx3, hist, out);
}

// Round 10
// 422.566 us; speedup vs baseline: 1.1047x; 1.1047x over previous
//
#include <hip/hip_runtime.h>
#include <hip/hip_bf16.h>
#include <math.h>

// Problem constants
#define N_E      16384
#define E_DIM    64
#define GROUPS   4
#define N_E_G    4096
#define NQ       16384     // B*H*W query vectors

// Output layout (element offsets into d_out, float32)
#define OFF_QUANT   0L
#define OFF_VQLOSS  4194304L
#define OFF_PERP    4194316L
#define OFF_MINENC  4194317L
#define OFF_IDX     71303181L
// zero region [OFF_VQLOSS, OFF_IDX): 67,108,877 floats, 16B-aligned start.
// 512 slices x 32768 float4 cover 67,108,864; 13-float tail by slice 0.

// Workspace layout (element offsets into d_ws as float*/int*)
#define WS_EN     0L          // normalized emb fp32 [4][4096][64] (plain)
#define WS_EN2    1048576L    // |e|^2 per code [16384]
#define WS_ENHI   1064960L    // bf16(en) ushort, FRAGMENT-ORDER layout
#define WS_HIST   1589248L    // int[4096]
#define WS_IDX3   1593344L    // int[16384]

typedef float  float4v  __attribute__((ext_vector_type(4)));
typedef short  short8   __attribute__((ext_vector_type(8)));

static __device__ __forceinline__ ushort f2bf(float x) {
    union { __hip_bfloat16 h; ushort u; } cv; cv.h = __float2bfloat16(x);
    return cv.u;
}

// Fragment-order offset for code c (0..4095 within group), k (0..63):
//   tile=c>>7, cq=(c>>5)&3, cs=(c>>4)&1, l15=c&15
//   ks=k>>5, quad=(k>>3)&3, j=k&7, lane=quad*16+l15
//   off = ((((tile*4+cq)*2+cs)*2+ks)*64 + lane)*8 + j
// => for fixed (tile,cq,cs,ks), 64 lanes read contiguous 16B chunks (1 KB).

// ---------------------------------------------------------------------------
// K0: blocks [0,4096) normalize embedding (one wave per code); writes en
// (plain fp32), en2, and ehi in fragment order. Block 4096 zeroes hist.
__global__ void norm_emb_kernel(const float* __restrict__ emb,
                                float* __restrict__ en, float* __restrict__ en2,
                                ushort* __restrict__ ehi, int* __restrict__ hist) {
    const int t = threadIdx.x;
    if (blockIdx.x == 4096) {
        for (int i = t; i < N_E_G; i += 256) hist[i] = 0;
        return;
    }
    int gid  = blockIdx.x * 256 + t;
    int code = gid >> 6;          // global code 0..16383
    int k    = t & 63;
    float x = emb[code * 64 + k];
    float ss = x * x;
    #pragma unroll
    for (int off = 32; off; off >>= 1) ss += __shfl_xor(ss, off, 64);
    float v = x / fmaxf(sqrtf(ss), 1e-12f);
    en[code * 64 + k] = v;
    {
        int g = code >> 12, c = code & 4095;
        int tile = c >> 7, cq = (c >> 5) & 3, cs = (c >> 4) & 1, l15 = c & 15;
        int ks = k >> 5, quad = (k >> 3) & 3, j = k & 7;
        int lane2 = quad * 16 + l15;
        size_t off = ((size_t)(((tile * 4 + cq) * 2 + cs) * 2 + ks) * 64 + lane2) * 8 + j;
        ehi[(size_t)g * 262144 + off] = f2bf(v);
    }
    float s2 = v * v;
    #pragma unroll
    for (int off = 32; off; off >>= 1) s2 += __shfl_xor(s2, off, 64);
    if (k == 0) en2[code] = s2;
}

// ---------------------------------------------------------------------------
// K1: fused z-norm + bf16-hi MFMA candidate generation + exact fp32 rescore.
// 512 blocks (128 queries x group), 512 threads = 8 waves mapped as
// qh (2 query-halves of 64) x cq (4 code-quarters of 32 per 128-tile).
// A-fragment loads are fully coalesced (fragment-order ehi): each load is a
// contiguous 1 KB wave read — fixes the 128B-lane-stride transaction stall
// that pinned rounds 4-9 at ~170 us K-loop.
// Capture: 4 streams/query (32-code columns), CAP 96 + per-stream-argmax
// insurance slots (overflow-safe). Rescore: 4 threads/query, exact fp32,
// order-independent (max d, then min idx) == np.argmax first-wins.
// In-loop 512 KB/block zero-fill (R8-proven hidden under compute).
// TAU >= 2*E, E = worst-case |dot - bf16hi-dot| <= 2*2^-8*(1+eps) = 7.83e-3.
#define CAP   96
#define CAPT  100      // CAP + 4 insurance slots
#define TAU   0.017f
__global__ __launch_bounds__(512, 4)
void vq_cand_kernel(const float* __restrict__ z, const ushort* __restrict__ ehi,
                    const float* __restrict__ en, const float* __restrict__ en2,
                    float* __restrict__ out,
                    int* __restrict__ hist, int* __restrict__ idx3) {
    __shared__ float  ztile[64][129];     // raw z, [d][q]   (33 KB)
    __shared__ float  rden[128];
    __shared__ int    cnt[128];
    __shared__ ushort cand[128 * CAPT];   // 25.6 KB
    __shared__ int    bks[128];
    __shared__ float  pv[512];
    __shared__ int    pk[512];

    const int g  = blockIdx.y;
    const int q0 = blockIdx.x * 128;
    const int t  = threadIdx.x;
    const int lane = t & 63;
    const int wave = t >> 6;
    const int l15 = lane & 15, quad = lane >> 4;
    const int qh = wave & 1;       // query half (64 queries)
    const int cq = wave >> 1;      // code quarter of each 128-tile (32 codes)

    const int sliceId = g * 128 + blockIdx.x;    // 0..511
    float4v* fill4 = (float4v*)(out + OFF_VQLOSS) + (size_t)sliceId * 32768;
    const float4v z4 = {0.f, 0.f, 0.f, 0.f};

    // stage raw z tile: [d][q], coalesced along hw
    {
        int b = q0 >> 10, hw0 = q0 & 1023;
        const float* zsrc = z + (size_t)b * 262144 + (size_t)g * 65536 + hw0;
        for (int i = t; i < 64 * 128; i += 512) {
            int d = i >> 7, q = i & 127;
            ztile[d][q] = zsrc[(size_t)d * 1024 + q];
        }
    }
    if (t < 128) cnt[t] = 0;
    __syncthreads();

    // per-query norms (sequential over d — bit-identical to rounds 1-9)
    if (t < 128) {
        float ss = 0.f;
        for (int d = 0; d < 64; ++d) {
            float x = ztile[d][t];
            ss = fmaf(x, x, ss);
        }
        rden[t] = fmaxf(sqrtf(ss), 1e-12f);
    }
    __syncthreads();

    // B-frags: this wave's 64 queries (4 x 16), built from LDS
    short8 bfrag[4][2];
    #pragma unroll
    for (int u = 0; u < 4; ++u) {
        int q = qh * 64 + u * 16 + l15;
        float den = rden[q];
        #pragma unroll
        for (int ks = 0; ks < 2; ++ks) {
            short8 f;
            #pragma unroll
            for (int j = 0; j < 8; ++j) {
                int k = ks * 32 + quad * 8 + j;
                f[j] = (short)f2bf(ztile[k][q] / den);
            }
            bfrag[u][ks] = f;
        }
    }

    const ushort* gbase = ehi + (size_t)g * 262144;

    float Mrun[4];
    float pbv[4];
    int   pbk[4];
    #pragma unroll
    for (int u = 0; u < 4; ++u) { Mrun[u] = -3.4e38f; pbv[u] = -3.4e38f; pbk[u] = 0; }

    for (int tile = 0; tile < 32; ++tile) {
        // A-frags: coalesced 1 KB wave loads (fragment-order layout)
        short8 af[2][2];
        #pragma unroll
        for (int cs = 0; cs < 2; ++cs)
            #pragma unroll
            for (int ks = 0; ks < 2; ++ks) {
                size_t o = ((size_t)(((tile * 4 + cq) * 2 + cs) * 2 + ks) * 64 + lane) * 8;
                af[cs][ks] = *(const short8*)(gbase + o);
            }
        // zero-fill slice: 2 float4 stores per thread per tile (hidden)
        fill4[(size_t)(tile * 2 + 0) * 512 + t] = z4;
        fill4[(size_t)(tile * 2 + 1) * 512 + t] = z4;

        float4v acc[2][4];
        #pragma unroll
        for (int cs = 0; cs < 2; ++cs)
            #pragma unroll
            for (int u = 0; u < 4; ++u) {
                float4v zz = {0.f, 0.f, 0.f, 0.f};
                float4v tmp = __builtin_amdgcn_mfma_f32_16x16x32_bf16(
                                  af[cs][0], bfrag[u][0], zz, 0, 0, 0);
                acc[cs][u] = __builtin_amdgcn_mfma_f32_16x16x32_bf16(
                                  af[cs][1], bfrag[u][1], tmp, 0, 0, 0);
            }

        // epilogue: running per-query max over this 32-code column + capture
        const int j0 = tile * 128 + cq * 32;
        #pragma unroll
        for (int u = 0; u < 4; ++u) {
            float m = acc[0][u][0];
            #pragma unroll
            for (int cs = 0; cs < 2; ++cs)
                #pragma unroll
                for (int r = 0; r < 4; ++r) {
                    float v = acc[cs][u][r];
                    m = fmaxf(m, v);
                    int ci = j0 + cs * 16 + quad * 4 + r;
                    if (v > pbv[u] || (v == pbv[u] && ci < pbk[u])) {
                        pbv[u] = v; pbk[u] = ci;
                    }
                }
            float m2 = fmaxf(m, __shfl_xor(m, 16, 64));
            float m4 = fmaxf(m2, __shfl_xor(m2, 32, 64));
            Mrun[u] = fmaxf(Mrun[u], m4);
            float thr = Mrun[u] - TAU;
            if (m >= thr) {                    // rare
                int ql = qh * 64 + u * 16 + l15;
                #pragma unroll
                for (int cs = 0; cs < 2; ++cs)
                    #pragma unroll
                    for (int r = 0; r < 4; ++r)
                        if (acc[cs][u][r] >= thr) {
                            int cidx = j0 + cs * 16 + quad * 4 + r;
                            int slot = atomicAdd(&cnt[ql], 1);
                            if (slot < CAP) cand[ql * CAPT + slot] = (ushort)cidx;
                        }
            }
        }
    }

    // insurance: per-stream (query, cq) bf16-argmax into slot CAP+cq
    #pragma unroll
    for (int u = 0; u < 4; ++u) {
        #pragma unroll
        for (int off = 16; off <= 32; off <<= 1) {
            float ov = __shfl_xor(pbv[u], off, 64);
            int   ok = __shfl_xor(pbk[u], off, 64);
            if (ov > pbv[u] || (ov == pbv[u] && ok < pbk[u])) { pbv[u] = ov; pbk[u] = ok; }
        }
        if (quad == 0) {
            int ql = qh * 64 + u * 16 + l15;
            cand[ql * CAPT + CAP + cq] = (ushort)pbk[u];
        }
    }
    __syncthreads();

    // exact fp32 rescore: 4 threads per query, order-independent rule
    {
        int tr = t >> 7, q = t & 127;
        float den = rden[q];
        float za[64];
        #pragma unroll
        for (int k = 0; k < 64; ++k) za[k] = ztile[k][q] / den;
        int nc = cnt[q]; if (nc > CAP) nc = CAP;
        float best = -3.4e38f; int bk = 0x7fffffff;
        for (int s = tr; s < nc + 4; s += 4) {
            int c = (s < nc) ? cand[q * CAPT + s] : cand[q * CAPT + CAP + (s - nc)];
            const float* ev = en + ((size_t)g * N_E_G + c) * 64;
            float a = 0.f;
            #pragma unroll
            for (int k = 0; k < 64; ++k) a = fmaf(za[k], ev[k], a);
            float d = 2.f * a - en2[g * N_E_G + c];
            if (d > best || (d == best && c < bk)) { best = d; bk = c; }
        }
        pv[t] = best; pk[t] = bk;
    }
    __syncthreads();

    if (t < 128) {
        float best = pv[t]; int bk = pk[t];
        #pragma unroll
        for (int tr = 1; tr < 4; ++tr) {
            float v = pv[tr * 128 + t]; int c = pk[tr * 128 + t];
            if (v > best || (v == best && c < bk)) { best = v; bk = c; }
        }
        bks[t] = bk;
        int q = q0 + t;
        out[OFF_IDX + (size_t)q * 4 + g] = (float)bk;
        if (g == 3) {
            idx3[q] = bk;
            atomicAdd(&hist[bk], 1);
        }
    }
    __syncthreads();

    // quant write, coalesced along hw
    for (int i = t; i < 128 * 64; i += 512) {
        int d = i >> 7, m = i & 127;
        int n = q0 + m, b = n >> 10, hw = n & 1023;
        out[OFF_QUANT + (size_t)b * 262144 + (size_t)(g * 64 + d) * 1024 + hw] =
            en[((size_t)g * N_E_G + bks[m]) * 64 + d];
    }

    // 13-float tail of the zero region
    if (sliceId == 0 && t < 13) out[OFF_VQLOSS + 67108864L + t] = 0.f;
}

// ---------------------------------------------------------------------------
// K2: scatter ones (64 blocks) + perplexity (block 64). Stream-ordered after
// vq_cand, so the zero-fill is complete and hist is final.
__global__ void finalize_kernel(const int* __restrict__ idx3,
                                const int* __restrict__ hist,
                                float* __restrict__ out) {
    if (blockIdx.x < 64) {
        int r = blockIdx.x * 256 + threadIdx.x;
        out[OFF_MINENC + (size_t)r * N_E_G + idx3[r]] = 1.0f;
        return;
    }
    __shared__ float s[256];
    int t = threadIdx.x;
    float acc = 0.f;
    for (int k = t; k < N_E_G; k += 256) {
        float p = (float)hist[k] * (1.0f / 16384.0f);
        acc += p * logf(p + 1e-10f);
    }
    s[t] = acc;
    __syncthreads();
    for (int o = 128; o; o >>= 1) {
        if (t < o) s[t] += s[t + o];
        __syncthreads();
    }
    if (t == 0) out[OFF_PERP] = expf(-s[0]);
}

// ---------------------------------------------------------------------------
extern "C" void kernel_launch(void* const* d_in, const int* in_sizes, int n_in,
                              void* d_out, int out_size, void* d_ws, size_t ws_size,
                              hipStream_t stream) {
    const float* z_groups = (const float*)d_in[0];
    const float* emb      = (const float*)d_in[1];
    float* out = (float*)d_out;
    float* ws  = (float*)d_ws;

    float*  en   = ws + WS_EN;
    float*  en2  = ws + WS_EN2;
    ushort* ehi  = (ushort*)(ws + WS_ENHI);
    int*    hist = (int*)(ws + WS_HIST);
    int*    idx3 = (int*)(ws + WS_IDX3);

    norm_emb_kernel<<<4097, 256, 0, stream>>>(emb, en, en2, ehi, hist);

    vq_cand_kernel<<<dim3(NQ / 128, GROUPS), 512, 0, stream>>>(
        z_groups, ehi, en, en2, out, hist, idx3);

    finalize_kernel<<<65, 256, 0, stream>>>(idx3, hist, out);
}